// Round 8
// baseline (736.153 us; speedup 1.0000x reference)
//
#include <hip/hip_runtime.h>
#include <hip/hip_bf16.h>
#include <math.h>
#include <string.h>

#define B_ 128
#define L_ 128
#define N_ 6
#define FA_ 39
#define FB_ 10
#define D_ 200
#define MB_ 256
#define R_ 3
#define T_ 2
#define NEGV -9e8f
#define BL_ (B_*L_)        // 16384
#define BLD_ (BL_*D_)      // 3276800
#define G3D_ (3*D_)        // 600
#define FP32TAG 0x3F800000u
#define CTXA 16            // atoms per block in k_ctxgemm
#define KP 416             // padded K for gate GEMM (400 -> 416 = 13*32)
#define NP 832             // padded N for gate GEMM (800 -> 832 = 13*64)

typedef __hip_bfloat16 bf16;
typedef __attribute__((ext_vector_type(8))) short short8;
typedef __attribute__((ext_vector_type(4))) float f32x4;

__device__ __forceinline__ float b2f(const bf16 x){ return __bfloat162float(x); }
__device__ __forceinline__ unsigned short f2b(float v){ bf16 t = __float2bfloat16(v); return *reinterpret_cast<unsigned short*>(&t); }
__device__ __forceinline__ float bu2f(unsigned short u){ unsigned x = ((unsigned)u)<<16; float f; memcpy(&f,&x,4); return f; }
__device__ __forceinline__ float lreluf(float x){ return x>=0.f ? x : 0.01f*x; }
__device__ __forceinline__ float eluf(float x){ return x>0.f ? x : expm1f(x); }
__device__ __forceinline__ float sigmf(float x){ return 1.f/(1.f+expf(-x)); }

#define NSEG 25
struct CvtArgs { const void* src[NSEG]; int ofs[NSEG+1]; };

#define PREPB_N (R_*NP*KP)     // 1038336
#define PREPM_N (D_*G3D_)      // 120000

// merged prep: [0,total) convert; [total, total+PREPB_N) build B2t; then mol-GRU transpose
__global__ void k_prep(CvtArgs c, float* __restrict__ dst,
                       const void* __restrict__ Wih, const void* __restrict__ Whh,
                       unsigned short* __restrict__ B2t,
                       const void* __restrict__ mWih_r, const void* __restrict__ mWhh_r,
                       float* __restrict__ mTi, float* __restrict__ mTh,
                       const unsigned* __restrict__ amtag, int total){
    int i = blockIdx.x*blockDim.x + threadIdx.x;
    bool f32 = (*amtag == FP32TAG);
    if (i < total){
        int s = 0;
        while (i >= c.ofs[s+1]) s++;
        int j = i - c.ofs[s];
        dst[i] = f32 ? ((const float*)c.src[s])[j] : b2f(((const bf16*)c.src[s])[j]);
        return;
    }
    int i2 = i - total;
    if (i2 < PREPB_N){
        int kk = i2 % KP;
        int rest = i2 / KP;
        int n = rest % NP;
        int r = rest / NP;
        float v = 0.f;
        if (kk < 200){
            if (n < 600){
                size_t si = ((size_t)(r*G3D_ + n))*D_ + kk;
                v = f32 ? ((const float*)Wih)[si] : b2f(((const bf16*)Wih)[si]);
            }
        } else if (kk < 400){
            int j = -1;
            if (n < 400) j = n;
            else if (n >= 600 && n < 800) j = n - 200;
            if (j >= 0){
                size_t si = ((size_t)(r*G3D_ + j))*D_ + (kk-200);
                v = f32 ? ((const float*)Whh)[si] : b2f(((const bf16*)Whh)[si]);
            }
        }
        B2t[i2] = f2b(v);
        return;
    }
    int i3 = i2 - PREPB_N;
    if (i3 < PREPM_N){
        int j = i3 % G3D_, k = i3 / G3D_;
        size_t si = (size_t)j*D_ + k;
        mTi[i3] = f32 ? ((const float*)mWih_r)[si] : b2f(((const bf16*)mWih_r)[si]);
        mTh[i3] = f32 ? ((const float*)mWhh_r)[si] : b2f(((const bf16*)mWhh_r)[si]);
    }
}

// fused init, wave-per-atom: atom_feature + P + XH h-half + XH pad + round-0 s1/tb dots
__global__ void __launch_bounds__(256) k_init(const float* __restrict__ atom_list,
                       const float* __restrict__ W_atom, const float* __restrict__ b_atom,
                       const float* __restrict__ W_nei, const float* __restrict__ b_nei,
                       const float* __restrict__ W_align,
                       float* __restrict__ h, float* __restrict__ cur,
                       unsigned short* __restrict__ XH, float* __restrict__ P,
                       float* __restrict__ s1, float* __restrict__ tb){
    int wv = threadIdx.x >> 6, lane = threadIdx.x & 63;
    int al = blockIdx.x*4 + wv;
    const float* arow = atom_list + (size_t)al*FA_;   // same addr across lanes -> broadcast
    float a1 = 0.f, a2 = 0.f;
    for (int d = lane; d < D_; d += 64){
        float acc1 = b_atom[d], acc2 = b_nei[d];
        for (int k=0;k<FA_;k++){
            float a = arow[k];
            acc1 += a * W_atom[k*D_ + d];
            acc2 += a * W_nei[k*D_ + d];
        }
        float v = lreluf(acc1);
        size_t gi = (size_t)al*D_ + d;
        h[gi] = v; cur[gi] = v;
        XH[(size_t)al*KP + 200 + d] = f2b(v);
        P[gi] = acc2;
        a1 += v * W_align[d];
        a2 += v * W_align[D_ + d];
    }
    if (lane < 16) XH[(size_t)al*KP + 400 + lane] = 0;
    for (int o=32;o>0;o>>=1){ a1 += __shfl_xor(a1,o); a2 += __shfl_xor(a2,o); }
    if (lane==0){ s1[al] = a1; tb[al] = a2; }
}

// attention: softmax + weighted neighbor sum. 4 atoms per 256-thread block, one wave per atom.
__global__ void __launch_bounds__(256) k_attn(
        const float* __restrict__ cur, const float* __restrict__ s1, const float* __restrict__ tb,
        const int* __restrict__ adl, const int* __restrict__ bdl,
        const float* __restrict__ P, const float* __restrict__ bond_list,
        const float* __restrict__ W_nei,
        const float* __restrict__ W_align, const float* __restrict__ b_align, int r,
        float* __restrict__ wnei, float* __restrict__ wsum){
    int wv = threadIdx.x >> 6;
    int lane = threadIdx.x & 63;
    int al = blockIdx.x*4 + wv;
    int bi = al >> 7;            // / L_
    __shared__ float s_nei[4][N_][D_];

    int idxn[N_]; bool pad[N_];
    for (int n=0;n<N_;n++){ idxn[n] = adl[al*N_ + n]; pad[n] = (idxn[n] == L_-1); }

    float s2[N_];
    if (r == 0){
        const float* Wb = W_nei + FA_*D_;
        for (int j = lane; j < N_*D_; j += 64){
            int n = j / D_, d = j - n*D_;
            int bd = bdl[al*N_ + n];
            const float* brow = bond_list + ((size_t)bi*MB_ + bd)*FB_;
            float acc = P[((size_t)bi*L_ + idxn[n])*D_ + d];
            #pragma unroll
            for (int k=0;k<FB_;k++) acc += brow[k] * Wb[k*D_ + d];
            s_nei[wv][n][d] = lreluf(acc);
        }
        const float* Wab = W_align + D_;
        for (int n=0;n<N_;n++){
            float acc = 0.f;
            for (int d=lane; d<D_; d+=64) acc += s_nei[wv][n][d] * Wab[d];
            for (int o=32;o>0;o>>=1) acc += __shfl_xor(acc,o);
            s2[n] = acc;
        }
    } else {
        float tmp = 0.f;
        if (lane < N_) tmp = tb[bi*L_ + idxn[lane]];
        for (int n=0;n<N_;n++) s2[n] = __shfl(tmp, n);
    }

    float s1v = s1[al];
    float bav = b_align[r];
    float a[N_]; float mx = -1e30f;
    for (int n=0;n<N_;n++){
        float v = lreluf(s1v + s2[n] + bav);
        if (pad[n]) v += NEGV;
        a[n] = v; mx = fmaxf(mx, v);
    }
    float w[N_]; float se = 0.f;
    for (int n=0;n<N_;n++){ float e = expf(a[n]-mx); w[n]=e; se += e; }
    float inv = 1.f/se; float wsv = 0.f;
    for (int n=0;n<N_;n++){ w[n] = pad[n] ? 0.f : w[n]*inv; wsv += w[n]; }

    if (r == 0){
        for (int d=lane; d<D_; d+=64){
            float acc = 0.f;
            #pragma unroll
            for (int n=0;n<N_;n++) acc += w[n] * s_nei[wv][n][d];
            wnei[(size_t)al*D_ + d] = acc;
        }
    } else {
        for (int d=lane; d<D_; d+=64){
            float acc = 0.f;
            #pragma unroll
            for (int n=0;n<N_;n++) acc += w[n] * cur[((size_t)bi*L_ + idxn[n])*D_ + d];
            wnei[(size_t)al*D_ + d] = acc;
        }
    }
    if (lane==0) wsum[al] = wsv;
}

// ctx = elu(wnei @ W_attend[r] + wsum * b_attend[r]) -> XH x-half (bf16)
__global__ void __launch_bounds__(256) k_ctxgemm(const float* __restrict__ wnei,
        const float* __restrict__ wsum,
        const float* __restrict__ W_attend, const float* __restrict__ b_attend, int r,
        unsigned short* __restrict__ XH){
    int tid = threadIdx.x;
    int al0 = blockIdx.x * CTXA;
    __shared__ float s_x[CTXA][D_];
    __shared__ float s_ws[CTXA];
    for (int i = tid; i < CTXA*D_; i += 256){
        int a = i / D_, d = i - a*D_;
        s_x[a][d] = wnei[(size_t)(al0+a)*D_ + d];
    }
    if (tid < CTXA) s_ws[tid] = wsum[al0 + tid];
    __syncthreads();
    int j = tid;
    if (j < D_){
        const float* W = W_attend + (size_t)r*D_*D_;
        float bv = b_attend[r*D_ + j];
        float acc[CTXA];
        #pragma unroll
        for (int a=0;a<CTXA;a++) acc[a] = 0.f;
        for (int k=0;k<D_;k+=4){
            float w0 = W[k*D_ + j], w1 = W[(k+1)*D_ + j];
            float w2 = W[(k+2)*D_ + j], w3 = W[(k+3)*D_ + j];
            #pragma unroll
            for (int a=0;a<CTXA;a++){
                float4 xv = *(const float4*)&s_x[a][k];
                acc[a] += xv.x*w0 + xv.y*w1 + xv.z*w2 + xv.w*w3;
            }
        }
        #pragma unroll
        for (int a=0;a<CTXA;a++)
            XH[(size_t)(al0+a)*KP + j] = f2b(eluf(acc[a] + s_ws[a]*bv));
    }
}

// MFMA bf16 gate GEMM: C[16384,NP] = XH[16384,KP] @ B2t[r]^T
__global__ void __launch_bounds__(256) k_gemm(const unsigned short* __restrict__ XH,
        const unsigned short* __restrict__ B2t, unsigned short* __restrict__ C, int r){
    __shared__ unsigned short As[64][40];
    __shared__ unsigned short Bs[64][40];
    int tid = threadIdx.x;
    int bid = blockIdx.x;
    int m0 = (bid & 255) * 64;
    int n0 = (bid >> 8) * 64;
    const unsigned short* Bt = B2t + (size_t)r*NP*KP;
    int lane = tid & 63, wm = tid >> 6;
    int quad = lane >> 4, lm = lane & 15;
    f32x4 acc0 = {0.f,0.f,0.f,0.f}, acc1 = acc0, acc2 = acc0, acc3 = acc0;
    int srow = tid >> 2, schunk = (tid & 3) * 8;
    for (int ks = 0; ks < 13; ks++){
        __syncthreads();
        *(uint4*)&As[srow][schunk] = *(const uint4*)&XH[(size_t)(m0 + srow)*KP + ks*32 + schunk];
        *(uint4*)&Bs[srow][schunk] = *(const uint4*)&Bt[(size_t)(n0 + srow)*KP + ks*32 + schunk];
        __syncthreads();
        short8 av = *(const short8*)&As[16*wm + lm][quad*8];
        short8 b0 = *(const short8*)&Bs[lm][quad*8];
        short8 b1 = *(const short8*)&Bs[16 + lm][quad*8];
        short8 b2 = *(const short8*)&Bs[32 + lm][quad*8];
        short8 b3 = *(const short8*)&Bs[48 + lm][quad*8];
        acc0 = __builtin_amdgcn_mfma_f32_16x16x32_bf16(av, b0, acc0, 0, 0, 0);
        acc1 = __builtin_amdgcn_mfma_f32_16x16x32_bf16(av, b1, acc1, 0, 0, 0);
        acc2 = __builtin_amdgcn_mfma_f32_16x16x32_bf16(av, b2, acc2, 0, 0, 0);
        acc3 = __builtin_amdgcn_mfma_f32_16x16x32_bf16(av, b3, acc3, 0, 0, 0);
    }
    #pragma unroll
    for (int i=0;i<4;i++){
        size_t rowbase = (size_t)(m0 + 16*wm + quad*4 + i)*NP + n0 + lm;
        C[rowbase      ] = f2b(acc0[i]);
        C[rowbase + 16 ] = f2b(acc1[i]);
        C[rowbase + 32 ] = f2b(acc2[i]);
        C[rowbase + 48 ] = f2b(acc3[i]);
    }
}

// GRU combine, wave-per-atom; fuses next-round s1/tb dots (r<2) or curdot (r==2)
__global__ void __launch_bounds__(256) k_gru2(const unsigned short* __restrict__ C,
        float* __restrict__ h, float* __restrict__ cur, unsigned short* __restrict__ XH,
        const float* __restrict__ bih, const float* __restrict__ bhh,
        const float* __restrict__ W_align, const float* __restrict__ Wma, int r,
        float* __restrict__ s1, float* __restrict__ tb, float* __restrict__ curdot){
    int wv = threadIdx.x >> 6, lane = threadIdx.x & 63;
    int al = blockIdx.x*4 + wv;
    size_t base = (size_t)al*NP;
    const float* bi = bih + r*G3D_;
    const float* bh = bhh + r*G3D_;
    const float* Wa = W_align + (r+1)*2*D_;   // dereferenced only when r<2
    bool last = (r == R_-1);
    float a1 = 0.f, a2 = 0.f;
    for (int j = lane; j < D_; j += 64){
        float rsum = bu2f(C[base + j]);
        float zsum = bu2f(C[base + 200 + j]);
        float gin  = bu2f(C[base + 400 + j]);
        float ghn  = bu2f(C[base + 600 + j]);
        float rr = sigmf(rsum + bi[j] + bh[j]);
        float zz = sigmf(zsum + bi[D_+j] + bh[D_+j]);
        float nn = tanhf(gin + bi[2*D_+j] + rr*(ghn + bh[2*D_+j]));
        size_t gi = (size_t)al*D_ + j;
        float hv = h[gi];
        float hn = (1.f-zz)*nn + zz*hv;
        h[gi] = hn;
        float cv = fmaxf(hn, 0.f);
        cur[gi] = cv;
        XH[(size_t)al*KP + 200 + j] = f2b(hn);
        if (last){
            a1 += cv * Wma[D_+j];
        } else {
            a1 += cv * Wa[j];
            a2 += cv * Wa[D_+j];
        }
    }
    for (int o=32;o>0;o>>=1){ a1 += __shfl_xor(a1,o); a2 += __shfl_xor(a2,o); }
    if (lane==0){
        if (last) curdot[al] = a1;
        else { s1[al] = a1; tb[al] = a2; }
    }
}

__device__ __forceinline__ float brSum(float v, float* s_red){
    for (int o=32;o>0;o>>=1) v += __shfl_xor(v,o);
    int lane = threadIdx.x & 63, wid = threadIdx.x >> 6;
    __syncthreads();
    if (lane==0) s_red[wid] = v;
    __syncthreads();
    float r = 0.f;
    int nw = blockDim.x >> 6;
    for (int i=0;i<nw;i++) r += s_red[i];
    return r;
}

__device__ __forceinline__ float brMax(float v, float* s_red){
    for (int o=32;o>0;o>>=1) v = fmaxf(v, __shfl_xor(v,o));
    int lane = threadIdx.x & 63, wid = threadIdx.x >> 6;
    __syncthreads();
    if (lane==0) s_red[wid] = v;
    __syncthreads();
    float r = s_red[0];
    int nw = blockDim.x >> 6;
    for (int i=1;i<nw;i++) r = fmaxf(r, s_red[i]);
    return r;
}

// molecule phase, 1024 threads/block (16 waves): every 200-deep loop split 4-way by chunk.
__global__ void __launch_bounds__(1024) k_mol(const float* __restrict__ cur,
    const float* __restrict__ curdot, const float* __restrict__ atom_mask,
    const float* __restrict__ Wma, const float* __restrict__ bma,
    const float* __restrict__ Wmt, const float* __restrict__ bmt,
    const float* __restrict__ mTi, const float* __restrict__ mTh,
    const float* __restrict__ mbih, const float* __restrict__ mbhh,
    const float* __restrict__ Wme, const float* __restrict__ bme,
    const float* __restrict__ Wout, const float* __restrict__ bout,
    void* __restrict__ out, const unsigned* __restrict__ amtag){
    int b = blockIdx.x, tid = threadIdx.x;
    int dq = tid & 255;       // d-role (active when < 200)
    int cq = tid >> 8;        // chunk 0..3
    __shared__ float s_am[L_], s_neg[L_], s_cd[L_], s_w[L_];
    __shared__ float s_mf[D_], s_act[D_], s_wc[D_], s_ctx[D_];
    __shared__ float s_gi[G3D_], s_gh[G3D_];
    __shared__ float s_part[4][256];
    __shared__ float s_red[16];
    const float* curb = cur + (size_t)b*L_*D_;
    if (tid < L_){
        float am = atom_mask[b*L_ + tid];
        s_am[tid] = am;
        s_neg[tid] = (am == 0.f) ? NEGV : 0.f;
        s_cd[tid] = curdot[b*L_ + tid];
    }
    __syncthreads();
    // masked pooling: (dq, cq) covers 32 l each
    {
        float acc = 0.f;
        if (dq < D_)
            for (int l=cq*32; l<cq*32+32; l++) acc += curb[(size_t)l*D_ + dq] * s_am[l];
        s_part[cq][dq] = acc;
        __syncthreads();
        if (tid < D_){
            float v = s_part[0][tid]+s_part[1][tid]+s_part[2][tid]+s_part[3][tid];
            s_mf[tid] = v; s_act[tid] = fmaxf(v, 0.f);
        }
        __syncthreads();
    }
    float bma0 = bma[0];
    for (int t=0;t<T_;t++){
        float p = (tid < D_) ? s_act[tid] * Wma[tid] : 0.f;
        float s1v = brSum(p, s_red);
        float sc = (tid < L_) ? (lreluf(s1v + s_cd[tid] + bma0) + s_neg[tid]) : -1e30f;
        float mx = brMax(sc, s_red);
        float e = (tid < L_) ? expf(sc - mx) : 0.f;
        float se = brSum(e, s_red);
        float wv_ = (tid < L_) ? e/se*s_am[tid] : 0.f;
        if (tid < L_) s_w[tid] = wv_;
        float wsm = brSum(wv_, s_red);
        __syncthreads();
        // weighted context sum: (dq, cq) x 32 l
        {
            float acc = 0.f;
            if (dq < D_)
                for (int l=cq*32; l<cq*32+32; l++) acc += s_w[l] * curb[(size_t)l*D_ + dq];
            s_part[cq][dq] = acc;
            __syncthreads();
            if (tid < D_) s_wc[tid] = s_part[0][tid]+s_part[1][tid]+s_part[2][tid]+s_part[3][tid];
            __syncthreads();
        }
        // ctx GEMV: (dq=j, cq) x 50 k
        {
            float acc = 0.f;
            if (dq < D_)
                for (int k=cq*50; k<cq*50+50; k++) acc += s_wc[k] * Wmt[(size_t)k*D_ + dq];
            s_part[cq][dq] = acc;
            __syncthreads();
            if (tid < D_){
                float v = s_part[0][tid]+s_part[1][tid]+s_part[2][tid]+s_part[3][tid]
                          + wsm * bmt[tid];
                s_ctx[tid] = eluf(v);
            }
            __syncthreads();
        }
        // gates: thread j < 600, full 200-k loop, 2 partial accumulators each for ILP
        if (tid < G3D_){
            float ai0=0.f, ai1=0.f, ah0=0.f, ah1=0.f;
            for (int k=0;k<D_;k+=2){
                ai0 += s_ctx[k]   * mTi[(size_t)k*G3D_ + tid];
                ai1 += s_ctx[k+1] * mTi[(size_t)(k+1)*G3D_ + tid];
                ah0 += s_mf[k]    * mTh[(size_t)k*G3D_ + tid];
                ah1 += s_mf[k+1]  * mTh[(size_t)(k+1)*G3D_ + tid];
            }
            s_gi[tid] = ai0+ai1; s_gh[tid] = ah0+ah1;
        }
        __syncthreads();
        if (tid < D_){
            int d = tid;
            float rr = sigmf(s_gi[d] + mbih[d] + s_gh[d] + mbhh[d]);
            float zz = sigmf(s_gi[D_+d] + mbih[D_+d] + s_gh[D_+d] + mbhh[D_+d]);
            float nn = tanhf(s_gi[2*D_+d] + mbih[2*D_+d] + rr*(s_gh[2*D_+d] + mbhh[2*D_+d]));
            float nm = (1.f-zz)*nn + zz*s_mf[d];
            s_mf[d] = nm; s_act[d] = fmaxf(nm, 0.f);
        }
        __syncthreads();
    }
    // head: (dq=d, cq) x 50 k over both Wme halves
    const float dd = (float)(R_ - 2);
    {
        float acc = 0.f;
        if (dq < D_)
            for (int k=cq*50; k<cq*50+50; k++){
                float mf = s_mf[k];
                acc += mf * Wme[(size_t)k*D_ + dq];
                acc += (mf + dd) * Wme[(size_t)(D_+k)*D_ + dq];
            }
        s_part[cq][dq] = acc;
        __syncthreads();
        float p = 0.f;
        if (tid < D_){
            float v = s_part[0][tid]+s_part[1][tid]+s_part[2][tid]+s_part[3][tid] + bme[tid];
            p = v * Wout[tid];
        }
        float o = brSum(p, s_red);
        if (tid==0){
            o += bout[0];
            if (*amtag == FP32TAG) ((float*)out)[b] = o;
            else ((bf16*)out)[b] = __float2bfloat16(o);
        }
    }
}

extern "C" void kernel_launch(void* const* d_in, const int* in_sizes, int n_in,
                              void* d_out, int out_size, void* d_ws, size_t ws_size,
                              hipStream_t stream) {
    const int* adl = (const int*)d_in[2];
    const int* bdl = (const int*)d_in[3];
    const unsigned* amtag = (const unsigned*)d_in[4];

    static const int srcidx[NSEG] = {0,1,4,5,6,7,8,9,10,11,12,15,16,17,18,19,20,21,22,23,24,25,26,27,28};
    static const int segsz[NSEG]  = {638976,327680,16384,7800,200,9800,200,1200,3,120000,600,
                                     1800,1800,400,1,40000,200,120000,120000,600,600,80000,200,200,1};
    CvtArgs ca;
    int ofs[NSEG+1]; ofs[0] = 0;
    for (int i=0;i<NSEG;i++){ ca.src[i] = d_in[srcidx[i]]; ca.ofs[i] = ofs[i]; ofs[i+1] = ofs[i] + segsz[i]; }
    ca.ofs[NSEG] = ofs[NSEG];
    const int total = ofs[NSEG];           // 1488645

    // ws layout (floats; offsets 16B aligned). ~76.5 MB total.
    float* ws   = (float*)d_ws;
    float* conv = ws;                                   // 1488648 (padded)
    float* h    = conv + 1488648;                       // BLD_
    float* cur  = h + BLD_;                             // BLD_
    unsigned short* XH  = (unsigned short*)(cur + BLD_);        // BL_*KP shorts
    unsigned short* B2t = XH + (size_t)BL_*KP;                  // R_*NP*KP shorts
    float* creg = (float*)(B2t + (size_t)R_*NP*KP);             // C region: BL_*NP shorts
    unsigned short* C = (unsigned short*)creg;
    float* wnei = creg;                                 // overlays C
    float* P    = creg + BLD_;                          // overlays C tail (round-0 only)
    float* s1   = creg + (size_t)BL_*NP/2;              // after C region
    float* tb   = s1 + BL_;
    float* wsum = tb + BL_;
    float* mTi  = wsum + BL_;                           // D_*G3D_ = 120000
    float* mTh  = mTi + D_*G3D_;
    float* curdot = mTh + D_*G3D_;                      // BL_

    const float* c_atom  = conv + ofs[0];
    const float* c_bond  = conv + ofs[1];
    const float* c_amask = conv + ofs[2];
    const float* c_Watom = conv + ofs[3];
    const float* c_batom = conv + ofs[4];
    const float* c_Wnei  = conv + ofs[5];
    const float* c_bnei  = conv + ofs[6];
    const float* c_Walign= conv + ofs[7];
    const float* c_balign= conv + ofs[8];
    const float* c_Watt  = conv + ofs[9];
    const float* c_batt  = conv + ofs[10];
    const float* c_bih   = conv + ofs[11];
    const float* c_bhh   = conv + ofs[12];
    const float* c_Wma   = conv + ofs[13];
    const float* c_bma   = conv + ofs[14];
    const float* c_Wmt   = conv + ofs[15];
    const float* c_bmt   = conv + ofs[16];
    const float* c_mbih  = conv + ofs[19];
    const float* c_mbhh  = conv + ofs[20];
    const float* c_Wme   = conv + ofs[21];
    const float* c_bme   = conv + ofs[22];
    const float* c_Wout  = conv + ofs[23];
    const float* c_bout  = conv + ofs[24];

    const int prep_total = total + PREPB_N + PREPM_N;   // 2646981
    k_prep<<<(prep_total + 255)/256, 256, 0, stream>>>(ca, conv, d_in[13], d_in[14], B2t,
                                                       d_in[21], d_in[22], mTi, mTh, amtag, total);
    k_init<<<BL_/4, 256, 0, stream>>>(c_atom, c_Watom, c_batom, c_Wnei, c_bnei, c_Walign,
                                      h, cur, XH, P, s1, tb);

    for (int r=0; r<R_; r++){
        k_attn<<<BL_/4, 256, 0, stream>>>(cur, s1, tb, adl, bdl, P, c_bond,
                                          c_Wnei, c_Walign, c_balign, r, wnei, wsum);
        k_ctxgemm<<<BL_/CTXA, 256, 0, stream>>>(wnei, wsum, c_Watt, c_batt, r, XH);
        k_gemm<<<(BL_/64)*(NP/64), 256, 0, stream>>>(XH, B2t, C, r);
        k_gru2<<<BL_/4, 256, 0, stream>>>(C, h, cur, XH, c_bih, c_bhh,
                                          c_Walign, c_Wma, r, s1, tb, curdot);
    }

    k_mol<<<B_, 1024, 0, stream>>>(cur, curdot, c_amask, c_Wma, c_bma, c_Wmt, c_bmt,
                                   mTi, mTh, c_mbih, c_mbhh, c_Wme, c_bme, c_Wout, c_bout,
                                   d_out, amtag);
}

// Round 9
// 560.743 us; speedup vs baseline: 1.3128x; 1.3128x over previous
//
#include <hip/hip_runtime.h>
#include <hip/hip_bf16.h>
#include <math.h>
#include <string.h>

#define B_ 128
#define L_ 128
#define N_ 6
#define FA_ 39
#define FB_ 10
#define D_ 200
#define MB_ 256
#define R_ 3
#define T_ 2
#define NEGV -9e8f
#define BL_ (B_*L_)        // 16384
#define BLD_ (BL_*D_)      // 3276800
#define G3D_ (3*D_)        // 600
#define FP32TAG 0x3F800000u
#define KP 416             // padded K for gate GEMM (400 -> 416 = 13*32)
#define NP 896             // padded N for gate GEMM (800 -> 896 = 7*128)
#define KC 224             // padded K for ctx GEMM (200 -> 224 = 7*32)
#define NC 256             // padded N for ctx GEMM (200 -> 256)

typedef __hip_bfloat16 bf16;
typedef __attribute__((ext_vector_type(8))) short short8;
typedef __attribute__((ext_vector_type(4))) float f32x4;

__device__ __forceinline__ float b2f(const bf16 x){ return __bfloat162float(x); }
__device__ __forceinline__ unsigned short f2b(float v){ bf16 t = __float2bfloat16(v); return *reinterpret_cast<unsigned short*>(&t); }
__device__ __forceinline__ float bu2f(unsigned short u){ unsigned x = ((unsigned)u)<<16; float f; memcpy(&f,&x,4); return f; }
__device__ __forceinline__ float lreluf(float x){ return x>=0.f ? x : 0.01f*x; }
__device__ __forceinline__ float eluf(float x){ return x>0.f ? x : expm1f(x); }
__device__ __forceinline__ float sigmf(float x){ return 1.f/(1.f+expf(-x)); }

#define NSEG 25
struct CvtArgs { const void* src[NSEG]; int ofs[NSEG+1]; };

#define PREPB_N (R_*NP*KP)     // 1118208
#define PREPM_N (D_*G3D_)      // 120000
#define PREPW_N (R_*NC*KC)     // 172032

// merged prep: convert -> B2t (gate weights) -> mol-GRU transpose -> WatT (ctx weights)
__global__ void k_prep(CvtArgs c, float* __restrict__ dst,
                       const void* __restrict__ Wih, const void* __restrict__ Whh,
                       unsigned short* __restrict__ B2t,
                       const void* __restrict__ mWih_r, const void* __restrict__ mWhh_r,
                       float* __restrict__ mTi, float* __restrict__ mTh,
                       const void* __restrict__ Watt_r, unsigned short* __restrict__ WatT,
                       const unsigned* __restrict__ amtag, int total){
    int i = blockIdx.x*blockDim.x + threadIdx.x;
    bool f32 = (*amtag == FP32TAG);
    if (i < total){
        int s = 0;
        while (i >= c.ofs[s+1]) s++;
        int j = i - c.ofs[s];
        dst[i] = f32 ? ((const float*)c.src[s])[j] : b2f(((const bf16*)c.src[s])[j]);
        return;
    }
    int i2 = i - total;
    if (i2 < PREPB_N){
        int kk = i2 % KP;
        int rest = i2 / KP;
        int n = rest % NP;
        int r = rest / NP;
        float v = 0.f;
        if (kk < 200){
            if (n < 600){
                size_t si = ((size_t)(r*G3D_ + n))*D_ + kk;
                v = f32 ? ((const float*)Wih)[si] : b2f(((const bf16*)Wih)[si]);
            }
        } else if (kk < 400){
            int j = -1;
            if (n < 400) j = n;
            else if (n >= 600 && n < 800) j = n - 200;
            if (j >= 0){
                size_t si = ((size_t)(r*G3D_ + j))*D_ + (kk-200);
                v = f32 ? ((const float*)Whh)[si] : b2f(((const bf16*)Whh)[si]);
            }
        }
        B2t[i2] = f2b(v);
        return;
    }
    int i3 = i2 - PREPB_N;
    if (i3 < PREPM_N){
        int j = i3 % G3D_, k = i3 / G3D_;
        size_t si = (size_t)j*D_ + k;
        mTi[i3] = f32 ? ((const float*)mWih_r)[si] : b2f(((const bf16*)mWih_r)[si]);
        mTh[i3] = f32 ? ((const float*)mWhh_r)[si] : b2f(((const bf16*)mWhh_r)[si]);
        return;
    }
    int i4 = i3 - PREPM_N;
    if (i4 < PREPW_N){
        int kk = i4 % KC;
        int rest = i4 / KC;
        int n = rest % NC;
        int r = rest / NC;
        float v = 0.f;
        if (kk < 200 && n < 200){
            size_t si = ((size_t)r*D_ + kk)*D_ + n;
            v = f32 ? ((const float*)Watt_r)[si] : b2f(((const bf16*)Watt_r)[si]);
        }
        WatT[i4] = f2b(v);
    }
}

// fused init, wave-per-atom: atom_feature + P + XH h-half + XH pad + round-0 s1/tb dots
__global__ void __launch_bounds__(256) k_init(const float* __restrict__ atom_list,
                       const float* __restrict__ W_atom, const float* __restrict__ b_atom,
                       const float* __restrict__ W_nei, const float* __restrict__ b_nei,
                       const float* __restrict__ W_align,
                       float* __restrict__ h, float* __restrict__ cur,
                       unsigned short* __restrict__ XH, float* __restrict__ P,
                       float* __restrict__ s1, float* __restrict__ tb){
    int wv = threadIdx.x >> 6, lane = threadIdx.x & 63;
    int al = blockIdx.x*4 + wv;
    const float* arow = atom_list + (size_t)al*FA_;
    float a1 = 0.f, a2 = 0.f;
    for (int d = lane; d < D_; d += 64){
        float acc1 = b_atom[d], acc2 = b_nei[d];
        for (int k=0;k<FA_;k++){
            float a = arow[k];
            acc1 += a * W_atom[k*D_ + d];
            acc2 += a * W_nei[k*D_ + d];
        }
        float v = lreluf(acc1);
        size_t gi = (size_t)al*D_ + d;
        h[gi] = v; cur[gi] = v;
        XH[(size_t)al*KP + 200 + d] = f2b(v);
        P[gi] = acc2;
        a1 += v * W_align[d];
        a2 += v * W_align[D_ + d];
    }
    if (lane < 16) XH[(size_t)al*KP + 400 + lane] = 0;
    for (int o=32;o>0;o>>=1){ a1 += __shfl_xor(a1,o); a2 += __shfl_xor(a2,o); }
    if (lane==0){ s1[al] = a1; tb[al] = a2; }
}

// attention: softmax + weighted neighbor sum -> bf16 wnei (stride KC, zero-padded tail)
__global__ void __launch_bounds__(256) k_attn(
        const float* __restrict__ cur, const float* __restrict__ s1, const float* __restrict__ tb,
        const int* __restrict__ adl, const int* __restrict__ bdl,
        const float* __restrict__ P, const float* __restrict__ bond_list,
        const float* __restrict__ W_nei,
        const float* __restrict__ W_align, const float* __restrict__ b_align, int r,
        unsigned short* __restrict__ wnei, float* __restrict__ wsum){
    int wv = threadIdx.x >> 6;
    int lane = threadIdx.x & 63;
    int al = blockIdx.x*4 + wv;
    int bi = al >> 7;            // / L_
    __shared__ float s_nei[4][N_][D_];

    int idxn[N_]; bool pad[N_];
    for (int n=0;n<N_;n++){ idxn[n] = adl[al*N_ + n]; pad[n] = (idxn[n] == L_-1); }

    float s2[N_];
    if (r == 0){
        const float* Wb = W_nei + FA_*D_;
        for (int j = lane; j < N_*D_; j += 64){
            int n = j / D_, d = j - n*D_;
            int bd = bdl[al*N_ + n];
            const float* brow = bond_list + ((size_t)bi*MB_ + bd)*FB_;
            float acc = P[((size_t)bi*L_ + idxn[n])*D_ + d];
            #pragma unroll
            for (int k=0;k<FB_;k++) acc += brow[k] * Wb[k*D_ + d];
            s_nei[wv][n][d] = lreluf(acc);
        }
        const float* Wab = W_align + D_;
        for (int n=0;n<N_;n++){
            float acc = 0.f;
            for (int d=lane; d<D_; d+=64) acc += s_nei[wv][n][d] * Wab[d];
            for (int o=32;o>0;o>>=1) acc += __shfl_xor(acc,o);
            s2[n] = acc;
        }
    } else {
        float tmp = 0.f;
        if (lane < N_) tmp = tb[bi*L_ + idxn[lane]];
        for (int n=0;n<N_;n++) s2[n] = __shfl(tmp, n);
    }

    float s1v = s1[al];
    float bav = b_align[r];
    float a[N_]; float mx = -1e30f;
    for (int n=0;n<N_;n++){
        float v = lreluf(s1v + s2[n] + bav);
        if (pad[n]) v += NEGV;
        a[n] = v; mx = fmaxf(mx, v);
    }
    float w[N_]; float se = 0.f;
    for (int n=0;n<N_;n++){ float e = expf(a[n]-mx); w[n]=e; se += e; }
    float inv = 1.f/se; float wsv = 0.f;
    for (int n=0;n<N_;n++){ w[n] = pad[n] ? 0.f : w[n]*inv; wsv += w[n]; }

    if (r == 0){
        for (int d=lane; d<D_; d+=64){
            float acc = 0.f;
            #pragma unroll
            for (int n=0;n<N_;n++) acc += w[n] * s_nei[wv][n][d];
            wnei[(size_t)al*KC + d] = f2b(acc);
        }
    } else {
        for (int d=lane; d<D_; d+=64){
            float acc = 0.f;
            #pragma unroll
            for (int n=0;n<N_;n++) acc += w[n] * cur[((size_t)bi*L_ + idxn[n])*D_ + d];
            wnei[(size_t)al*KC + d] = f2b(acc);
        }
    }
    if (lane < 24) wnei[(size_t)al*KC + 200 + lane] = 0;
    if (lane==0) wsum[al] = wsv;
}

// MFMA ctx GEMM: elu(wnei[16384,KC] @ WatT[r]^T + wsum*b_attend) -> XH x-half.
// 128x64 tile; wave: 32 rows x 64 cols (2 m-subs x 4 n-subs).
__global__ void __launch_bounds__(256) k_ctxmfma(const unsigned short* __restrict__ Wn,
        const float* __restrict__ wsum, const unsigned short* __restrict__ WatT,
        const float* __restrict__ b_attend, int r, unsigned short* __restrict__ XH){
    __shared__ unsigned short As[128][40];
    __shared__ unsigned short Bs[64][40];
    int tid = threadIdx.x;
    int m0 = (blockIdx.x & 127) * 128;
    int n0 = (blockIdx.x >> 7) * 64;
    const unsigned short* Bt = WatT + (size_t)r*NC*KC;
    int lane = tid & 63, wv = tid >> 6;
    int quad = lane >> 4, lm = lane & 15;
    f32x4 acc[2][4];
    #pragma unroll
    for (int a=0;a<2;a++)
        #pragma unroll
        for (int b=0;b<4;b++) acc[a][b] = (f32x4){0.f,0.f,0.f,0.f};
    int ar0 = tid >> 1;                 // A: 128 rows x 2 slots (16 shorts each)... use 4-chunk map
    (void)ar0;
    for (int ks = 0; ks < 7; ks++){
        int s0 = tid, s1_ = tid + 256;
        int r0_ = s0 >> 2, c0 = (s0 & 3) * 8;
        int r1_ = s1_ >> 2, c1 = (s1_ & 3) * 8;
        uint4 a0 = *(const uint4*)&Wn[(size_t)(m0 + r0_)*KC + ks*32 + c0];
        uint4 a1 = *(const uint4*)&Wn[(size_t)(m0 + r1_)*KC + ks*32 + c1];
        uint4 b0 = *(const uint4*)&Bt[(size_t)(n0 + (tid >> 2))*KC + ks*32 + (tid & 3)*8];
        __syncthreads();
        *(uint4*)&As[r0_][c0] = a0;
        *(uint4*)&As[r1_][c1] = a1;
        *(uint4*)&Bs[tid >> 2][(tid & 3)*8] = b0;
        __syncthreads();
        short8 av0 = *(const short8*)&As[wv*32 + lm][quad*8];
        short8 av1 = *(const short8*)&As[wv*32 + 16 + lm][quad*8];
        #pragma unroll
        for (int ns=0; ns<4; ns++){
            short8 bv = *(const short8*)&Bs[ns*16 + lm][quad*8];
            acc[0][ns] = __builtin_amdgcn_mfma_f32_16x16x32_bf16(av0, bv, acc[0][ns], 0,0,0);
            acc[1][ns] = __builtin_amdgcn_mfma_f32_16x16x32_bf16(av1, bv, acc[1][ns], 0,0,0);
        }
    }
    #pragma unroll
    for (int ms=0; ms<2; ms++)
      #pragma unroll
      for (int ns=0; ns<4; ns++){
        int n = n0 + ns*16 + lm;
        if (n < 200){
            float bv = b_attend[r*D_ + n];
            #pragma unroll
            for (int i=0;i<4;i++){
                int row = m0 + wv*32 + ms*16 + quad*4 + i;
                float v = acc[ms][ns][i] + wsum[row]*bv;
                XH[(size_t)row*KP + n] = f2b(eluf(v));
            }
        }
      }
}

// MFMA gate GEMM: C[16384,NP] = XH[16384,KP] @ B2t[r]^T. 128x128 tile;
// wave: 32 rows x 128 cols (2 m-subs x 8 n-subs), K-steps of 32.
__global__ void __launch_bounds__(256) k_gemm(const unsigned short* __restrict__ XH,
        const unsigned short* __restrict__ B2t, unsigned short* __restrict__ C, int r){
    __shared__ unsigned short As[128][40];
    __shared__ unsigned short Bs[128][40];
    int tid = threadIdx.x;
    int m0 = (blockIdx.x & 127) * 128;
    int n0 = (blockIdx.x >> 7) * 128;
    const unsigned short* Bt = B2t + (size_t)r*NP*KP;
    int lane = tid & 63, wv = tid >> 6;
    int quad = lane >> 4, lm = lane & 15;
    f32x4 acc[2][8];
    #pragma unroll
    for (int a=0;a<2;a++)
        #pragma unroll
        for (int b=0;b<8;b++) acc[a][b] = (f32x4){0.f,0.f,0.f,0.f};
    for (int ks = 0; ks < 13; ks++){
        int s0 = tid, s1_ = tid + 256;
        int r0_ = s0 >> 2, c0 = (s0 & 3) * 8;
        int r1_ = s1_ >> 2, c1 = (s1_ & 3) * 8;
        uint4 a0 = *(const uint4*)&XH[(size_t)(m0 + r0_)*KP + ks*32 + c0];
        uint4 a1 = *(const uint4*)&XH[(size_t)(m0 + r1_)*KP + ks*32 + c1];
        uint4 b0 = *(const uint4*)&Bt[(size_t)(n0 + r0_)*KP + ks*32 + c0];
        uint4 b1 = *(const uint4*)&Bt[(size_t)(n0 + r1_)*KP + ks*32 + c1];
        __syncthreads();
        *(uint4*)&As[r0_][c0] = a0;
        *(uint4*)&As[r1_][c1] = a1;
        *(uint4*)&Bs[r0_][c0] = b0;
        *(uint4*)&Bs[r1_][c1] = b1;
        __syncthreads();
        short8 av0 = *(const short8*)&As[wv*32 + lm][quad*8];
        short8 av1 = *(const short8*)&As[wv*32 + 16 + lm][quad*8];
        #pragma unroll
        for (int ns=0; ns<8; ns++){
            short8 bv = *(const short8*)&Bs[ns*16 + lm][quad*8];
            acc[0][ns] = __builtin_amdgcn_mfma_f32_16x16x32_bf16(av0, bv, acc[0][ns], 0,0,0);
            acc[1][ns] = __builtin_amdgcn_mfma_f32_16x16x32_bf16(av1, bv, acc[1][ns], 0,0,0);
        }
    }
    #pragma unroll
    for (int ms=0; ms<2; ms++)
      #pragma unroll
      for (int ns=0; ns<8; ns++)
        #pragma unroll
        for (int i=0;i<4;i++){
            int row = m0 + wv*32 + ms*16 + quad*4 + i;
            C[(size_t)row*NP + n0 + ns*16 + lm] = f2b(acc[ms][ns][i]);
        }
}

// GRU combine, wave-per-atom; fuses next-round s1/tb dots (r<2) or curdot (r==2)
__global__ void __launch_bounds__(256) k_gru2(const unsigned short* __restrict__ C,
        float* __restrict__ h, float* __restrict__ cur, unsigned short* __restrict__ XH,
        const float* __restrict__ bih, const float* __restrict__ bhh,
        const float* __restrict__ W_align, const float* __restrict__ Wma, int r,
        float* __restrict__ s1, float* __restrict__ tb, float* __restrict__ curdot){
    int wv = threadIdx.x >> 6, lane = threadIdx.x & 63;
    int al = blockIdx.x*4 + wv;
    size_t base = (size_t)al*NP;
    const float* bi = bih + r*G3D_;
    const float* bh = bhh + r*G3D_;
    const float* Wa = W_align + (r+1)*2*D_;   // dereferenced only when r<2
    bool last = (r == R_-1);
    float a1 = 0.f, a2 = 0.f;
    for (int j = lane; j < D_; j += 64){
        float rsum = bu2f(C[base + j]);
        float zsum = bu2f(C[base + 200 + j]);
        float gin  = bu2f(C[base + 400 + j]);
        float ghn  = bu2f(C[base + 600 + j]);
        float rr = sigmf(rsum + bi[j] + bh[j]);
        float zz = sigmf(zsum + bi[D_+j] + bh[D_+j]);
        float nn = tanhf(gin + bi[2*D_+j] + rr*(ghn + bh[2*D_+j]));
        size_t gi = (size_t)al*D_ + j;
        float hv = h[gi];
        float hn = (1.f-zz)*nn + zz*hv;
        h[gi] = hn;
        float cv = fmaxf(hn, 0.f);
        cur[gi] = cv;
        XH[(size_t)al*KP + 200 + j] = f2b(hn);
        if (last){
            a1 += cv * Wma[D_+j];
        } else {
            a1 += cv * Wa[j];
            a2 += cv * Wa[D_+j];
        }
    }
    for (int o=32;o>0;o>>=1){ a1 += __shfl_xor(a1,o); a2 += __shfl_xor(a2,o); }
    if (lane==0){
        if (last) curdot[al] = a1;
        else { s1[al] = a1; tb[al] = a2; }
    }
}

__device__ __forceinline__ float brSum(float v, float* s_red){
    for (int o=32;o>0;o>>=1) v += __shfl_xor(v,o);
    int lane = threadIdx.x & 63, wid = threadIdx.x >> 6;
    __syncthreads();
    if (lane==0) s_red[wid] = v;
    __syncthreads();
    float r = 0.f;
    int nw = blockDim.x >> 6;
    for (int i=0;i<nw;i++) r += s_red[i];
    return r;
}

__device__ __forceinline__ float brMax(float v, float* s_red){
    for (int o=32;o>0;o>>=1) v = fmaxf(v, __shfl_xor(v,o));
    int lane = threadIdx.x & 63, wid = threadIdx.x >> 6;
    __syncthreads();
    if (lane==0) s_red[wid] = v;
    __syncthreads();
    float r = s_red[0];
    int nw = blockDim.x >> 6;
    for (int i=1;i<nw;i++) r = fmaxf(r, s_red[i]);
    return r;
}

// molecule phase (reverted to the proven 256-thread round-7 version; 1024-thread variant spilled)
__global__ void __launch_bounds__(256) k_mol(const float* __restrict__ cur,
    const float* __restrict__ curdot, const float* __restrict__ atom_mask,
    const float* __restrict__ Wma, const float* __restrict__ bma,
    const float* __restrict__ Wmt, const float* __restrict__ bmt,
    const float* __restrict__ mTi, const float* __restrict__ mTh,
    const float* __restrict__ mbih, const float* __restrict__ mbhh,
    const float* __restrict__ Wme, const float* __restrict__ bme,
    const float* __restrict__ Wout, const float* __restrict__ bout,
    void* __restrict__ out, const unsigned* __restrict__ amtag){
    int b = blockIdx.x, tid = threadIdx.x;
    __shared__ float s_am[L_], s_neg[L_], s_cd[L_], s_w[L_];
    __shared__ float s_mf[D_], s_act[D_], s_wc[D_], s_ctx[D_];
    __shared__ float s_gi[G3D_], s_gh[G3D_], s_red[8];
    const float* curb = cur + (size_t)b*L_*D_;
    if (tid < L_){
        float am = atom_mask[b*L_ + tid];
        s_am[tid] = am;
        s_neg[tid] = (am == 0.f) ? NEGV : 0.f;
        s_cd[tid] = curdot[b*L_ + tid];
    }
    __syncthreads();
    for (int d=tid; d<D_; d+=256){
        float acc = 0.f;
        for (int l=0;l<L_;l++) acc += curb[l*D_ + d] * s_am[l];
        s_mf[d] = acc; s_act[d] = fmaxf(acc, 0.f);
    }
    __syncthreads();
    float bma0 = bma[0];
    for (int t=0;t<T_;t++){
        float p = 0.f;
        for (int d=tid; d<D_; d+=256) p += s_act[d] * Wma[d];
        float s1v = brSum(p, s_red);
        float sc = (tid < L_) ? (lreluf(s1v + s_cd[tid] + bma0) + s_neg[tid]) : -1e30f;
        float mx = brMax(sc, s_red);
        float e = (tid < L_) ? expf(sc - mx) : 0.f;
        float se = brSum(e, s_red);
        float wv_ = (tid < L_) ? e/se*s_am[tid] : 0.f;
        if (tid < L_) s_w[tid] = wv_;
        float wsm = brSum(wv_, s_red);
        __syncthreads();
        for (int d=tid; d<D_; d+=256){
            float acc = 0.f;
            for (int l=0;l<L_;l++) acc += s_w[l]*curb[l*D_ + d];
            s_wc[d] = acc;
        }
        __syncthreads();
        if (tid < D_){
            float acc = wsm * bmt[tid];
            for (int k=0;k<D_;k++) acc += s_wc[k] * Wmt[k*D_ + tid];
            s_ctx[tid] = eluf(acc);
        }
        __syncthreads();
        for (int j=tid; j<G3D_; j+=256){
            float ai0=0.f, ai1=0.f, ah0=0.f, ah1=0.f;
            for (int k=0;k<D_;k+=2){
                ai0 += s_ctx[k]   * mTi[(size_t)k*G3D_ + j];
                ai1 += s_ctx[k+1] * mTi[(size_t)(k+1)*G3D_ + j];
                ah0 += s_mf[k]    * mTh[(size_t)k*G3D_ + j];
                ah1 += s_mf[k+1]  * mTh[(size_t)(k+1)*G3D_ + j];
            }
            s_gi[j] = ai0+ai1; s_gh[j] = ah0+ah1;
        }
        __syncthreads();
        if (tid < D_){
            int d = tid;
            float rr = sigmf(s_gi[d] + mbih[d] + s_gh[d] + mbhh[d]);
            float zz = sigmf(s_gi[D_+d] + mbih[D_+d] + s_gh[D_+d] + mbhh[D_+d]);
            float nn = tanhf(s_gi[2*D_+d] + mbih[2*D_+d] + rr*(s_gh[2*D_+d] + mbhh[2*D_+d]));
            float nm = (1.f-zz)*nn + zz*s_mf[d];
            s_mf[d] = nm; s_act[d] = fmaxf(nm, 0.f);
        }
        __syncthreads();
    }
    const float dd = (float)(R_ - 2);
    float p = 0.f;
    for (int d=tid; d<D_; d+=256){
        float acc = bme[d];
        for (int k=0;k<D_;k++){
            float mf = s_mf[k];
            acc += mf * Wme[k*D_ + d];
            acc += (mf + dd) * Wme[(D_+k)*D_ + d];
        }
        p += acc * Wout[d];
    }
    float o = brSum(p, s_red);
    if (tid==0){
        o += bout[0];
        if (*amtag == FP32TAG) ((float*)out)[b] = o;
        else ((bf16*)out)[b] = __float2bfloat16(o);
    }
}

extern "C" void kernel_launch(void* const* d_in, const int* in_sizes, int n_in,
                              void* d_out, int out_size, void* d_ws, size_t ws_size,
                              hipStream_t stream) {
    const int* adl = (const int*)d_in[2];
    const int* bdl = (const int*)d_in[3];
    const unsigned* amtag = (const unsigned*)d_in[4];

    static const int srcidx[NSEG] = {0,1,4,5,6,7,8,9,10,11,12,15,16,17,18,19,20,21,22,23,24,25,26,27,28};
    static const int segsz[NSEG]  = {638976,327680,16384,7800,200,9800,200,1200,3,120000,600,
                                     1800,1800,400,1,40000,200,120000,120000,600,600,80000,200,200,1};
    CvtArgs ca;
    int ofs[NSEG+1]; ofs[0] = 0;
    for (int i=0;i<NSEG;i++){ ca.src[i] = d_in[srcidx[i]]; ca.ofs[i] = ofs[i]; ofs[i+1] = ofs[i] + segsz[i]; }
    ca.ofs[NSEG] = ofs[NSEG];
    const int total = ofs[NSEG];           // 1488645

    // ws layout (floats; offsets multiples of 4 -> 16B aligned). ~79.0 MB total.
    float* ws   = (float*)d_ws;
    float* conv = ws;                                    // 1488648
    float* h    = conv + 1488648;                        // BLD_
    float* cur  = h + BLD_;                              // BLD_
    unsigned short* XH   = (unsigned short*)(cur + BLD_);        // BL_*KP shorts = 3407872 fl
    unsigned short* B2t  = XH + (size_t)BL_*KP;                  // PREPB_N shorts = 559104 fl
    unsigned short* WatT = B2t + PREPB_N;                        // PREPW_N shorts = 86016 fl
    float* creg = (float*)(WatT + PREPW_N);              // C region: BL_*NP shorts = 7340032 fl
    unsigned short* C = (unsigned short*)creg;
    unsigned short* wnei = (unsigned short*)creg;        // BL_*KC shorts, overlays C head
    float* P    = creg + 1900032;                        // BLD_, overlays C mid (round-0 only)
    float* s1   = creg + 7340032;                        // after C region
    float* tb   = s1 + BL_;
    float* wsum = tb + BL_;
    float* mTi  = wsum + BL_;                            // 120000
    float* mTh  = mTi + D_*G3D_;
    float* curdot = mTh + D_*G3D_;                       // BL_

    const float* c_atom  = conv + ofs[0];
    const float* c_bond  = conv + ofs[1];
    const float* c_amask = conv + ofs[2];
    const float* c_Watom = conv + ofs[3];
    const float* c_batom = conv + ofs[4];
    const float* c_Wnei  = conv + ofs[5];
    const float* c_bnei  = conv + ofs[6];
    const float* c_Walign= conv + ofs[7];
    const float* c_balign= conv + ofs[8];
    const float* c_batt  = conv + ofs[10];
    const float* c_bih   = conv + ofs[11];
    const float* c_bhh   = conv + ofs[12];
    const float* c_Wma   = conv + ofs[13];
    const float* c_bma   = conv + ofs[14];
    const float* c_Wmt   = conv + ofs[15];
    const float* c_bmt   = conv + ofs[16];
    const float* c_mbih  = conv + ofs[19];
    const float* c_mbhh  = conv + ofs[20];
    const float* c_Wme   = conv + ofs[21];
    const float* c_bme   = conv + ofs[22];
    const float* c_Wout  = conv + ofs[23];
    const float* c_bout  = conv + ofs[24];

    const int prep_total = total + PREPB_N + PREPM_N + PREPW_N;   // 2898885
    k_prep<<<(prep_total + 255)/256, 256, 0, stream>>>(ca, conv, d_in[13], d_in[14], B2t,
                                                       d_in[21], d_in[22], mTi, mTh,
                                                       d_in[11], WatT, amtag, total);
    k_init<<<BL_/4, 256, 0, stream>>>(c_atom, c_Watom, c_batom, c_Wnei, c_bnei, c_Walign,
                                      h, cur, XH, P, s1, tb);

    for (int r=0; r<R_; r++){
        k_attn<<<BL_/4, 256, 0, stream>>>(cur, s1, tb, adl, bdl, P, c_bond,
                                          c_Wnei, c_Walign, c_balign, r, wnei, wsum);
        k_ctxmfma<<<(BL_/128)*(NC/64), 256, 0, stream>>>(wnei, wsum, WatT, c_batt, r, XH);
        k_gemm<<<(BL_/128)*(NP/128), 256, 0, stream>>>(XH, B2t, C, r);
        k_gru2<<<BL_/4, 256, 0, stream>>>(C, h, cur, XH, c_bih, c_bhh,
                                          c_Walign, c_Wma, r, s1, tb, curdot);
    }

    k_mol<<<B_, 256, 0, stream>>>(cur, curdot, c_amask, c_Wma, c_bma, c_Wmt, c_bmt,
                                  mTi, mTh, c_mbih, c_mbhh, c_Wme, c_bme, c_Wout, c_bout,
                                  d_out, amtag);
}